// Round 1
// baseline (3088.188 us; speedup 1.0000x reference)
//
#include <hip/hip_runtime.h>
#include <stdint.h>

typedef unsigned long long u64;
typedef int v4i  __attribute__((ext_vector_type(4)));
typedef int v8i  __attribute__((ext_vector_type(8)));
typedef float v16f __attribute__((ext_vector_type(16)));

// MX-fp4 MFMA, scales = 1.0 (E8M0 127 in every byte), fmt 4 = FP4 for A and B.
// Data duplicated into both halves of the 8-reg operand to be robust to the
// fp4 register-placement convention ([0:3] vs [4:7]).
static __device__ __forceinline__ v16f mfma_fp4(v4i a, v4i b, v16f c) {
    v8i A, B;
    A[0] = a[0]; A[1] = a[1]; A[2] = a[2]; A[3] = a[3];
    A[4] = a[0]; A[5] = a[1]; A[6] = a[2]; A[7] = a[3];
    B[0] = b[0]; B[1] = b[1]; B[2] = b[2]; B[3] = b[3];
    B[4] = b[0]; B[5] = b[1]; B[6] = b[2]; B[7] = b[3];
    return __builtin_amdgcn_mfma_scale_f32_32x32x64_f8f6f4(
        A, B, c, 4, 4, 0, 0x7F7F7F7F, 0, 0x7F7F7F7F);
}

static __device__ __forceinline__ void gload_lds16(const void* g, void* l) {
    __builtin_amdgcn_global_load_lds(
        (const __attribute__((address_space(1))) unsigned int*)g,
        (__attribute__((address_space(3))) unsigned int*)l, 16, 0, 0);
}

// ---------------------------------------------------------------------------
// Pack input x [256,3,32,32] f32 -> A0 [256][32][32][1] u64 (bits 0..2 = sign>0)
// ---------------------------------------------------------------------------
__global__ void pack_input_kernel(const float* __restrict__ x, u64* __restrict__ a0)
{
    int idx = blockIdx.x * blockDim.x + threadIdx.x;
    if (idx >= 256 * 1024) return;
    int b = idx >> 10, pix = idx & 1023;
    const float* xp = x + (size_t)b * 3072 + pix;
    u64 wd = 0;
    if (xp[0]    > 0.f) wd |= 1ull;
    if (xp[1024] > 0.f) wd |= 2ull;
    if (xp[2048] > 0.f) wd |= 4ull;
    a0[idx] = wd;
}

// ---------------------------------------------------------------------------
// w [O][C][3][3] f32 -> fp4 B-fragment slab:
//   unit = (t*KWIN + c64)*OCG + og, 1024 B each (64 lanes x 16 B).
//   lane: oc = og*32 + (lane&31), K-half h = lane>>5.
//   dword d, nibble j  <->  channel c = c64*64 + h*32 + d*8 + ((j>>1)+(j&1)*4)
//   nibble: +1 -> 0x2, -1 -> 0xA, invalid channel/oc -> 0x0.
// ---------------------------------------------------------------------------
__global__ void pack_w_fp4(const float* __restrict__ w, unsigned* __restrict__ wb,
                           int O, int C, int KWIN, int OCG)
{
    int idx = blockIdx.x * blockDim.x + threadIdx.x;
    int total = 9 * KWIN * OCG * 64;
    if (idx >= total) return;
    int lane = idx & 63;
    int rest = idx >> 6;
    int og = rest % OCG; rest /= OCG;
    int c64 = rest % KWIN; int t = rest / KWIN;
    int oc = og * 32 + (lane & 31);
    int h = lane >> 5;
    unsigned out[4];
#pragma unroll
    for (int d = 0; d < 4; ++d) {
        unsigned dw = 0;
#pragma unroll
        for (int j = 0; j < 8; ++j) {
            int c = c64 * 64 + h * 32 + d * 8 + ((j >> 1) + (j & 1) * 4);
            unsigned nib = 0;
            if (oc < O && c < C)
                nib = (w[(size_t)(oc * C + c) * 9 + t] > 0.f) ? 0x2u : 0xAu;
            dw |= nib << (4 * j);
        }
        out[d] = dw;
    }
    *(v4i*)(wb + (size_t)idx * 4) = *(v4i*)out;
}

// ---------------------------------------------------------------------------
// BN -> (scale, offset): bn(y) = y*sa + sb
// ---------------------------------------------------------------------------
__global__ void pack_bn_kernel(const float* __restrict__ p, float* __restrict__ sa,
                               float* __restrict__ sb, int C)
{
    int i = blockIdx.x * blockDim.x + threadIdx.x;
    if (i >= C) return;
    float g = p[i], b = p[C + i], m = p[2 * C + i], v = p[3 * C + i];
    float s = g * rsqrtf(v + 1e-5f);
    sa[i] = s;
    sb[i] = fmaf(-m, s, b);
}

// ---------------------------------------------------------------------------
// Pack fc weights [10][15568] f32 -> [10][16 pix][16 words] u64
// ---------------------------------------------------------------------------
__global__ void pack_fc_kernel(const float* __restrict__ fcw, u64* __restrict__ wfc)
{
    int idx = blockIdx.x * blockDim.x + threadIdx.x;
    if (idx >= 10 * 256) return;
    int w = idx & 15;
    int p = (idx >> 4) & 15;
    int k = idx >> 8;
    u64 word = 0;
    for (int c2 = 0; c2 < 64; ++c2) {
        int c = w * 64 + c2;
        if (c < 973) {
            if (fcw[(size_t)k * 15568 + c * 16 + p] > 0.f) word |= (1ull << c2);
        }
    }
    wfc[idx] = word;
}

// ---------------------------------------------------------------------------
// 32 sign bits -> 32 fp4 nibbles (16 B), channel order d*8 + perm(j),
// perm(j) = (j>>1)+(j&1)*4 (matches pack_w_fp4). bit=1 -> 0x2 (+1), else 0xA.
// ---------------------------------------------------------------------------
static __device__ __forceinline__ v4i fp4_unpack32(unsigned wh)
{
    v4i r;
#pragma unroll
    for (int d = 0; d < 4; ++d) {
        unsigned b = (wh >> (8 * d)) & 0xffu;
        unsigned lo = ((b & 0xFu) * 0x00204081u) & 0x01010101u;
        unsigned hi = ((b >> 4)   * 0x00204081u) & 0x01010101u;
        unsigned spread = lo | (hi << 4);
        r[d] = (int)(0xAAAAAAAAu - (spread << 3));
    }
    return r;
}

// ---------------------------------------------------------------------------
// fp4 conv, big layers, SOFTWARE-PIPELINED (double-buffered LDS):
// per chunk c: issue act loads(c+1) + B-DMA(c+1 -> buf^1), run 9-tap MFMA
// phase on buf, then unpack+ds_write A(c+1), one barrier. OOB halo cells are
// zero-filled once in the prologue (both buffers). KWIN==1 keeps 1 buffer.
// ---------------------------------------------------------------------------
template <int H, int W, int TH, int TW, int NIMG, int KWIN, int OCG_T, int OCW,
          int COUT, bool POOL>
__global__ __launch_bounds__(256, 2)
void conv_v6f(const u64* __restrict__ act, const char* __restrict__ wb,
              const float* __restrict__ sA, const float* __restrict__ sB,
              u64* __restrict__ outp)
{
    constexpr int CW = TW + 2;
    constexpr int CELLS_I = (TH + 2) * CW;
    constexpr int CELLS = NIMG * CELLS_I;
    constexpr int PLANE = CELLS * 16;
    constexpr int BSZ = 18432;              // 18 units x 1KB
    constexpr int BUF = BSZ + 2 * PLANE;
    constexpr int NBUF = (KWIN > 1) ? 2 : 1;
    constexpr int NCELL = (CELLS + 255) / 256;
    __shared__ __attribute__((aligned(16))) char smem[NBUF * BUF];

    const int tid  = threadIdx.x;
    const int lane = tid & 63;
    const int wm   = tid >> 6;
    const int h    = lane >> 5;
    const int m    = lane & 31;

    int b0i, y0;
    if constexpr (NIMG == 1) {
        b0i = blockIdx.x >> 1;
        y0 = (blockIdx.x & 1) * TH;
    } else {
        b0i = blockIdx.x * NIMG;
        y0 = 0;
    }

    const int ocg0 = blockIdx.y * 2;
    const int gw   = blockIdx.y;

    int aoff[4];
#pragma unroll
    for (int ag = 0; ag < 4; ++ag) {
        int p = wm * 128 + ag * 32 + m;
        int img = p / (TH * TW);
        int pp = p % (TH * TW);
        aoff[ag] = ((img * CELLS_I + (pp / TW) * CW + (pp % TW)) << 4) + h * PLANE;
    }

    // ---- precompute per-thread act-cell pointers; zero OOB cells once ----
    const u64* cp[NCELL];
    int  coff[NCELL];
    bool cval[NCELL];
#pragma unroll
    for (int i = 0; i < NCELL; ++i) {
        cval[i] = false; cp[i] = act; coff[i] = 0;
        int cell = tid + i * 256;
        if (cell < CELLS) {
            int img, c2;
            if constexpr (NIMG == 1) { img = 0; c2 = cell; }
            else { img = cell / CELLS_I; c2 = cell % CELLS_I; }
            int cy = c2 / CW, cx = c2 % CW;
            int gy = y0 + cy - 1, gx = cx - 1;
            coff[i] = cell * 16;
            if ((unsigned)gy < (unsigned)H && (unsigned)gx < (unsigned)W) {
                cval[i] = true;
                cp[i] = act + ((size_t)(b0i + img) * H * W + (size_t)gy * W + gx) * KWIN;
            } else {
                v4i z = {0, 0, 0, 0};
                *(v4i*)(smem + BSZ + cell * 16)         = z;
                *(v4i*)(smem + BSZ + cell * 16 + PLANE) = z;
                if constexpr (NBUF == 2) {
                    *(v4i*)(smem + BUF + BSZ + cell * 16)         = z;
                    *(v4i*)(smem + BUF + BSZ + cell * 16 + PLANE) = z;
                }
            }
        }
    }

    // ---- per-wave B DMA source pointers (chunk 0) + prologue stage ----
    const char* bsrc[5];
#pragma unroll
    for (int k = 0; k < 5; ++k) {
        const int u = wm + 4 * k;
        if (u < 18) {
            const int og = u & 1, t = u >> 1;
            bsrc[k] = wb + ((size_t)(t * KWIN * OCG_T + ocg0 + og)) * 1024 + lane * 16;
            gload_lds16(bsrc[k], smem + u * 1024);
        } else {
            bsrc[k] = wb;
        }
    }
    {
        u64 wd0[NCELL];
#pragma unroll
        for (int i = 0; i < NCELL; ++i) wd0[i] = cval[i] ? cp[i][0] : 0;
#pragma unroll
        for (int i = 0; i < NCELL; ++i) if (cval[i]) {
            char* dst = smem + BSZ + coff[i];
            *(v4i*)dst           = fp4_unpack32((unsigned)wd0[i]);
            *(v4i*)(dst + PLANE) = fp4_unpack32((unsigned)(wd0[i] >> 32));
        }
    }
    __syncthreads();   // drains DMA (vmcnt) + LDS writes

    v16f acc[4][2];
#pragma unroll
    for (int ag = 0; ag < 4; ++ag)
#pragma unroll
        for (int o = 0; o < 2; ++o)
#pragma unroll
            for (int i = 0; i < 16; ++i) acc[ag][o][i] = 0.0f;

#pragma unroll 1
    for (int c64 = 0; c64 < KWIN; ++c64) {
        const int cur = c64 & 1;
        const char* sb = smem + cur * BUF;
        char* nb = smem + ((NBUF == 2) ? ((cur ^ 1) * BUF) : 0);
        const bool more = (c64 + 1 < KWIN);

        // ---- issue next-chunk staging early: act loads to regs, B via DMA ----
        u64 wd[NCELL];
        if (more) {
#pragma unroll
            for (int i = 0; i < NCELL; ++i) wd[i] = cval[i] ? cp[i][c64 + 1] : 0;
#pragma unroll
            for (int k = 0; k < 5; ++k) {
                const int u = wm + 4 * k;
                if (u < 18) {
                    bsrc[k] += (size_t)OCG_T * 1024;
                    gload_lds16(bsrc[k], nb + u * 1024);
                }
            }
        }

        // ---- K-steps: one tap = one K=64 MFMA per acc tile ----
#pragma unroll
        for (int t = 0; t < 9; ++t) {
            const int aimm = BSZ + (((t / 3) * CW) + (t % 3)) * 16;
            v4i b0 = *(const v4i*)(sb + (t * 2 + 0) * 1024 + lane * 16);
            v4i b1 = *(const v4i*)(sb + (t * 2 + 1) * 1024 + lane * 16);
            v4i a0 = *(const v4i*)(sb + aoff[0] + aimm);
            v4i a1 = *(const v4i*)(sb + aoff[1] + aimm);
            v4i a2 = *(const v4i*)(sb + aoff[2] + aimm);
            v4i a3 = *(const v4i*)(sb + aoff[3] + aimm);
            acc[0][0] = mfma_fp4(a0, b0, acc[0][0]);
            acc[1][0] = mfma_fp4(a1, b0, acc[1][0]);
            acc[2][0] = mfma_fp4(a2, b0, acc[2][0]);
            acc[3][0] = mfma_fp4(a3, b0, acc[3][0]);
            acc[0][1] = mfma_fp4(a0, b1, acc[0][1]);
            acc[1][1] = mfma_fp4(a1, b1, acc[1][1]);
            acc[2][1] = mfma_fp4(a2, b1, acc[2][1]);
            acc[3][1] = mfma_fp4(a3, b1, acc[3][1]);
        }

        // ---- late half of the stage: unpack + ds_write A(c+1) ----
        if (more) {
#pragma unroll
            for (int i = 0; i < NCELL; ++i) if (cval[i]) {
                char* dst = nb + BSZ + coff[i];
                *(v4i*)dst           = fp4_unpack32((unsigned)wd[i]);
                *(v4i*)(dst + PLANE) = fp4_unpack32((unsigned)(wd[i] >> 32));
            }
            __syncthreads();   // drains DMA (vmcnt) + LDS writes for buf^1
        }
    }

    // ---- epilogue: (pool) + BN-sign -> ballot-packed u64 stores ----
    const int ocA = ocg0 * 32 + m;
    const int ocB = ocA + 32;
    const float fa0 = sA[ocA < COUT ? ocA : 0], fb0 = sB[ocA < COUT ? ocA : 0];
    const float fa1 = sA[ocB < COUT ? ocB : 0], fb1 = sB[ocB < COUT ? ocB : 0];

#pragma unroll
    for (int ag = 0; ag < 4; ++ag) {
        if constexpr (POOL && TW == 32) {
            if (ag & 1) continue;   // vertical pool pairs rows (ag, ag+1)
#pragma unroll
            for (int gi = 0; gi < 8; ++gi) {
                const int g = gi * 2;
                float v0 = fmaxf(fmaxf(acc[ag][0][g], acc[ag][0][g ^ 1]),
                                 fmaxf(acc[ag + 1][0][g], acc[ag + 1][0][g ^ 1]));
                float v1 = fmaxf(fmaxf(acc[ag][1][g], acc[ag][1][g ^ 1]),
                                 fmaxf(acc[ag + 1][1][g], acc[ag + 1][1][g ^ 1]));
                u64 bal0 = __ballot((ocA < COUT) && (fmaf(v0, fa0, fb0) > 0.f));
                u64 bal1 = __ballot((ocB < COUT) && (fmaf(v1, fa1, fb1) > 0.f));
                u64 w_lo = (bal0 & 0xffffffffull) | (bal1 << 32);
                u64 w_hi = (bal0 >> 32) | (bal1 & 0xffffffff00000000ull);
                int pyo  = wm * 2 + (ag >> 1);
                int pxo0 = ((g & 3) >> 1) + 4 * (g >> 2);
                size_t rowb = ((size_t)b0i * (H / 2) + (y0 / 2 + pyo)) * (W / 2);
                if (lane == (ag >> 1) * 16 + gi * 2)
                    outp[(rowb + pxo0) * OCW + gw] = w_lo;
                else if (lane == (ag >> 1) * 16 + gi * 2 + 1)
                    outp[(rowb + pxo0 + 2) * OCW + gw] = w_hi;
            }
        } else if constexpr (POOL) {   // TW == 16, NIMG images
#pragma unroll
            for (int gi = 0; gi < 4; ++gi) {
                const int g = gi * 2;
                float v0 = fmaxf(fmaxf(acc[ag][0][g], acc[ag][0][g ^ 1]),
                                 fmaxf(acc[ag][0][g ^ 8], acc[ag][0][(g ^ 8) | 1]));
                float v1 = fmaxf(fmaxf(acc[ag][1][g], acc[ag][1][g ^ 1]),
                                 fmaxf(acc[ag][1][g ^ 8], acc[ag][1][(g ^ 8) | 1]));
                u64 bal0 = __ballot((ocA < COUT) && (fmaf(v0, fa0, fb0) > 0.f));
                u64 bal1 = __ballot((ocB < COUT) && (fmaf(v1, fa1, fb1) > 0.f));
                u64 w_lo = (bal0 & 0xffffffffull) | (bal1 << 32);
                u64 w_hi = (bal0 >> 32) | (bal1 & 0xffffffff00000000ull);
                int img  = wm >> 1;
                int pyo  = (wm & 1) * 4 + ag;
                int pxo0 = ((g >> 1) & 1) | (((g >> 2) & 1) << 2);
                size_t rowb = ((size_t)(b0i + img) * (TH / 2) + pyo) * (TW / 2);
                if (lane == (ag * 4 + gi) * 2)
                    outp[(rowb + pxo0) * OCW + gw] = w_lo;
                else if (lane == (ag * 4 + gi) * 2 + 1)
                    outp[(rowb + pxo0 + 2) * OCW + gw] = w_hi;
            }
        } else {
#pragma unroll
            for (int reg = 0; reg < 16; ++reg) {
                u64 bal0 = __ballot((ocA < COUT) && (fmaf(acc[ag][0][reg], fa0, fb0) > 0.f));
                u64 bal1 = __ballot((ocB < COUT) && (fmaf(acc[ag][1][reg], fa1, fb1) > 0.f));
                u64 w_lo = (bal0 & 0xffffffffull) | (bal1 << 32);
                u64 w_hi = (bal0 >> 32) | (bal1 & 0xffffffff00000000ull);
                int row  = (reg & 3) + 8 * (reg >> 2);
                int p_lo = wm * 128 + ag * 32 + row;
                int p_hi = p_lo + 4;
                if (lane == reg * 2) {
                    int img, py, px;
                    if constexpr (TW == 32) { img = 0; py = p_lo >> 5; px = p_lo & 31; }
                    else { img = p_lo >> 8; py = (p_lo >> 4) & 15; px = p_lo & 15; }
                    outp[(((size_t)(b0i + img) * H + (y0 + py)) * W + px) * OCW + gw] = w_lo;
                } else if (lane == reg * 2 + 1) {
                    int img, py, px;
                    if constexpr (TW == 32) { img = 0; py = p_hi >> 5; px = p_hi & 31; }
                    else { img = p_hi >> 8; py = (p_hi >> 4) & 15; px = p_hi & 15; }
                    outp[(((size_t)(b0i + img) * H + (y0 + py)) * W + px) * OCW + gw] = w_hi;
                }
            }
        }
    }
}

// ---------------------------------------------------------------------------
// fp4 8x8-layer conv: block = 4 waves = 4 images x 64 oc; wave = own image.
// LDS is wave-private -> no block barriers: wave-level lgkmcnt fences only
// (DS ops from one wave complete in order). Act words for chunk c+1 are
// prefetched into regs before the tap phase, written after it (T14 split).
// ---------------------------------------------------------------------------
template <int KWIN, int OCG, int OCW, int COUT, bool POOL>
__global__ __launch_bounds__(256, 3)
void conv_m8f(const u64* __restrict__ act, const char* __restrict__ wb,
              const float* __restrict__ sA, const float* __restrict__ sB,
              u64* __restrict__ outp)
{
    constexpr int CELLS = 100;
    constexpr int PLANE = CELLS * 16;
    constexpr int IMG = 2 * PLANE;
    __shared__ __attribute__((aligned(16))) char smem[4 * IMG];

    const int tid  = threadIdx.x;
    const int lane = tid & 63;
    const int wave = tid >> 6;
    const int h    = lane >> 5;
    const int m    = lane & 31;

    const int b = blockIdx.x * 4 + wave;
    const int ocg0 = blockIdx.y * 2;
    const int gw = blockIdx.y;

    int aoff[2];
#pragma unroll
    for (int ph = 0; ph < 2; ++ph) {
        int p = ph * 32 + m;
        aoff[ph] = wave * IMG + ((p >> 3) * 10 + (p & 7)) * 16 + h * PLANE;
    }

    const u64* actb = act + (size_t)b * (64 * KWIN);

    // ---- per-lane cell info; zero OOB cells once ----
    const u64* cp0 = actb; int co0; bool cv0;
    const u64* cp1 = actb; int co1 = 0; bool cv1 = false;
    {
        int cy = lane / 10, cx = lane % 10;
        int gy = cy - 1, gx = cx - 1;
        co0 = wave * IMG + lane * 16;
        cv0 = ((unsigned)gy < 8u && (unsigned)gx < 8u);
        if (cv0) {
            cp0 = actb + ((size_t)(gy * 8 + gx)) * KWIN;
        } else {
            v4i z = {0, 0, 0, 0};
            *(v4i*)(smem + co0)         = z;
            *(v4i*)(smem + co0 + PLANE) = z;
        }
        int cell1 = lane + 64;
        if (cell1 < CELLS) {
            int cy1 = cell1 / 10, cx1 = cell1 % 10;
            int gy1 = cy1 - 1, gx1 = cx1 - 1;
            co1 = wave * IMG + cell1 * 16;
            cv1 = ((unsigned)gy1 < 8u && (unsigned)gx1 < 8u);
            if (cv1) {
                cp1 = actb + ((size_t)(gy1 * 8 + gx1)) * KWIN;
            } else {
                v4i z = {0, 0, 0, 0};
                *(v4i*)(smem + co1)         = z;
                *(v4i*)(smem + co1 + PLANE) = z;
            }
        }
    }

    v16f acc[2][2];
#pragma unroll
    for (int a = 0; a < 2; ++a)
#pragma unroll
        for (int o = 0; o < 2; ++o)
#pragma unroll
            for (int i = 0; i < 16; ++i) acc[a][o][i] = 0.0f;

    v4i b0n, b1n;
    {
        const v4i* pn = (const v4i*)(wb + ((size_t)ocg0) * 1024) + lane;
        b0n = pn[0]; b1n = pn[64];
    }

    // ---- prologue: stage chunk 0 ----
    {
        u64 w0 = cv0 ? cp0[0] : 0;
        u64 w1 = cv1 ? cp1[0] : 0;
        if (cv0) {
            char* d = smem + co0;
            *(v4i*)d           = fp4_unpack32((unsigned)w0);
            *(v4i*)(d + PLANE) = fp4_unpack32((unsigned)(w0 >> 32));
        }
        if (cv1) {
            char* d = smem + co1;
            *(v4i*)d           = fp4_unpack32((unsigned)w1);
            *(v4i*)(d + PLANE) = fp4_unpack32((unsigned)(w1 >> 32));
        }
    }
    asm volatile("s_waitcnt lgkmcnt(0)" ::: "memory");
    __builtin_amdgcn_sched_barrier(0);

#pragma unroll 1
    for (int c64 = 0; c64 < KWIN; ++c64) {
        const bool more = (c64 + 1 < KWIN);
        u64 nw0 = 0, nw1 = 0;
        if (more) {
            nw0 = cv0 ? cp0[c64 + 1] : 0;
            nw1 = cv1 ? cp1[c64 + 1] : 0;
        }

#pragma unroll
        for (int t = 0; t < 9; ++t) {
            v4i b0 = b0n, b1 = b1n;
            {
                const int tn = (t + 1) % 9;
                const int cn = (t == 8) ? (c64 + 1) : c64;
                const v4i* pn = (const v4i*)(wb + ((size_t)((tn * KWIN + cn) * OCG + ocg0)) * 1024) + lane;
                b0n = pn[0]; b1n = pn[64];
            }
            const int toff = ((t / 3) * 10 + (t % 3)) * 16;
            v4i a0 = *(const v4i*)(smem + aoff[0] + toff);
            v4i a1 = *(const v4i*)(smem + aoff[1] + toff);
            acc[0][0] = mfma_fp4(a0, b0, acc[0][0]);
            acc[1][0] = mfma_fp4(a1, b0, acc[1][0]);
            acc[0][1] = mfma_fp4(a0, b1, acc[0][1]);
            acc[1][1] = mfma_fp4(a1, b1, acc[1][1]);
        }

        // fence: keep next-chunk ds_writes after this chunk's ds_reads
        asm volatile("s_waitcnt lgkmcnt(0)" ::: "memory");
        __builtin_amdgcn_sched_barrier(0);
        if (more) {
            if (cv0) {
                char* d = smem + co0;
                *(v4i*)d           = fp4_unpack32((unsigned)nw0);
                *(v4i*)(d + PLANE) = fp4_unpack32((unsigned)(nw0 >> 32));
            }
            if (cv1) {
                char* d = smem + co1;
                *(v4i*)d           = fp4_unpack32((unsigned)nw1);
                *(v4i*)(d + PLANE) = fp4_unpack32((unsigned)(nw1 >> 32));
            }
            asm volatile("s_waitcnt lgkmcnt(0)" ::: "memory");
            __builtin_amdgcn_sched_barrier(0);
        }
    }

    const int ocA = ocg0 * 32 + m;
    const int ocB = ocA + 32;
    const float fa0 = sA[ocA < COUT ? ocA : 0], fb0 = sB[ocA < COUT ? ocA : 0];
    const float fa1 = sA[ocB < COUT ? ocB : 0], fb1 = sB[ocB < COUT ? ocB : 0];

#pragma unroll
    for (int ph = 0; ph < 2; ++ph) {
        if constexpr (POOL) {
#pragma unroll
            for (int gi = 0; gi < 4; ++gi) {
                const int g = (gi & 1) * 2 + (gi >> 1) * 8;
                float v0 = fmaxf(fmaxf(acc[ph][0][g], acc[ph][0][g ^ 1]),
                                 fmaxf(acc[ph][0][g ^ 4], acc[ph][0][(g ^ 4) | 1]));
                float v1 = fmaxf(fmaxf(acc[ph][1][g], acc[ph][1][g ^ 1]),
                                 fmaxf(acc[ph][1][g ^ 4], acc[ph][1][(g ^ 4) | 1]));
                u64 bal0 = __ballot((ocA < COUT) && (fmaf(v0, fa0, fb0) > 0.f));
                u64 bal1 = __ballot((ocB < COUT) && (fmaf(v1, fa1, fb1) > 0.f));
                u64 w_lo = (bal0 & 0xffffffffull) | (bal1 << 32);
                u64 w_hi = (bal0 >> 32) | (bal1 & 0xffffffff00000000ull);
                int pyo  = ph * 2 + ((g >> 3) & 1);
                int pxo0 = (g >> 1) & 1;
                int pxo1 = pxo0 | 2;
                size_t rowb = ((size_t)b * 4 + pyo) * 4;
                if (lane == (ph * 4 + gi) * 2)
                    outp[(rowb + pxo0) * OCW + gw] = w_lo;
                else if (lane == (ph * 4 + gi) * 2 + 1)
                    outp[(rowb + pxo1) * OCW + gw] = w_hi;
            }
        } else {
#pragma unroll
            for (int reg = 0; reg < 16; ++reg) {
                u64 bal0 = __ballot((ocA < COUT) && (fmaf(acc[ph][0][reg], fa0, fb0) > 0.f));
                u64 bal1 = __ballot((ocB < COUT) && (fmaf(acc[ph][1][reg], fa1, fb1) > 0.f));
                u64 w_lo = (bal0 & 0xffffffffull) | (bal1 << 32);
                u64 w_hi = (bal0 >> 32) | (bal1 & 0xffffffff00000000ull);
                int row  = (reg & 3) + 8 * (reg >> 2);
                int p_lo = ph * 32 + row;
                int p_hi = p_lo + 4;
                if (lane == reg * 2)
                    outp[(((size_t)b * 8 + (p_lo >> 3)) * 8 + (p_lo & 7)) * OCW + gw] = w_lo;
                else if (lane == reg * 2 + 1)
                    outp[(((size_t)b * 8 + (p_hi >> 3)) * 8 + (p_hi & 7)) * OCW + gw] = w_hi;
            }
        }
    }
}

// ---------------------------------------------------------------------------
// FC: out[b][k] = 15568 - 2*popcount(a6[b] ^ wfc[k]) + fcb[k]   (exact)
// ---------------------------------------------------------------------------
__global__ void fc_kernel(const u64* __restrict__ a6, const u64* __restrict__ wfc,
                          const float* __restrict__ fcb, float* __restrict__ out)
{
    int idx = blockIdx.x * blockDim.x + threadIdx.x;
    if (idx >= 2560) return;
    int k = idx % 10, b = idx / 10;
    const u64* ap = a6 + (size_t)b * 256;
    const u64* wq = wfc + (size_t)k * 256;
    int pop = 0;
#pragma unroll 8
    for (int q = 0; q < 256; ++q) pop += __popcll(ap[q] ^ wq[q]);
    out[idx] = (float)(15568 - 2 * pop) + fcb[k];
}

// ---------------------------------------------------------------------------
// launch
// ---------------------------------------------------------------------------
extern "C" void kernel_launch(void* const* d_in, const int* in_sizes, int n_in,
                              void* d_out, int out_size, void* d_ws, size_t ws_size,
                              hipStream_t stream)
{
    const float* x   = (const float*)d_in[0];
    const float* w0  = (const float*)d_in[1];
    const float* p0  = (const float*)d_in[2];
    const float* w1  = (const float*)d_in[3];
    const float* p1  = (const float*)d_in[4];
    const float* w2  = (const float*)d_in[5];
    const float* p2  = (const float*)d_in[6];
    const float* w3  = (const float*)d_in[7];
    const float* p3  = (const float*)d_in[8];
    const float* w4  = (const float*)d_in[9];
    const float* p4  = (const float*)d_in[10];
    const float* w5  = (const float*)d_in[11];
    const float* p5  = (const float*)d_in[12];
    const float* fcw = (const float*)d_in[13];
    const float* fcb = (const float*)d_in[14];
    float* out = (float*)d_out;

    u64* WS = (u64*)d_ws;
    u64* A0 = WS;                  // [256][32][32][1]  = 262144
    u64* A1 = A0 + 262144;         // [256][32][32][6]  = 1572864
    u64* A2 = A1 + 1572864;        // [256][16][16][6]  = 393216
    u64* A3 = A2 + 393216;         // [256][16][16][11] = 720896
    u64* A4 = A3 + 720896;         // [256][8][8][11]   = 180224
    u64* A5 = A4 + 180224;         // [256][8][8][20]   = 327680
    u64* A6 = A5 + 327680;         // [256][4][4][16]   = 65536
    u64* WFp = A6 + 65536;         // 2560
    // fp4 weight slabs: 9*KWIN*OCG KB each
    char* WB0 = (char*)(WFp + 2560);   //   110,592 (KWIN=1,  OCG=12)
    char* WB1 = WB0 + 110592;          //   663,552 (KWIN=6,  OCG=12)
    char* WB2 = WB1 + 663552;          // 1,327,104 (KWIN=6,  OCG=24)
    char* WB3 = WB2 + 1327104;         // 2,433,024 (KWIN=11, OCG=24)
    char* WB4 = WB3 + 2433024;         // 4,055,040 (KWIN=11, OCG=40)
    char* WB5 = WB4 + 4055040;         // 5,898,240 (KWIN=20, OCG=32)
    float* SA0 = (float*)(WB5 + 5898240);
    float* SB0 = SA0 + 1280;
    float* SA1 = SB0 + 1280;
    float* SB1 = SA1 + 1280;
    float* SA2 = SB1 + 1280;
    float* SB2 = SA2 + 1280;
    float* SA3 = SB2 + 1280;
    float* SB3 = SA3 + 1280;
    float* SA4 = SB3 + 1280;
    float* SB4 = SA4 + 1280;
    float* SA5 = SB4 + 1280;
    float* SB5 = SA5 + 1280;
    // total ws ~= 43 MB

    pack_input_kernel<<<1024, 256, 0, stream>>>(x, A0);
    pack_w_fp4<<<(9 * 1 * 12 * 64 + 255) / 256, 256, 0, stream>>>(w0, (unsigned*)WB0, 344, 3, 1, 12);
    pack_w_fp4<<<(9 * 6 * 12 * 64 + 255) / 256, 256, 0, stream>>>(w1, (unsigned*)WB1, 352, 344, 6, 12);
    pack_w_fp4<<<(9 * 6 * 24 * 64 + 255) / 256, 256, 0, stream>>>(w2, (unsigned*)WB2, 686, 352, 6, 24);
    pack_w_fp4<<<(9 * 11 * 24 * 64 + 255) / 256, 256, 0, stream>>>(w3, (unsigned*)WB3, 679, 686, 11, 24);
    pack_w_fp4<<<(9 * 11 * 40 * 64 + 255) / 256, 256, 0, stream>>>(w4, (unsigned*)WB4, 1246, 679, 11, 40);
    pack_w_fp4<<<(9 * 20 * 32 * 64 + 255) / 256, 256, 0, stream>>>(w5, (unsigned*)WB5, 973, 1246, 20, 32);
    pack_bn_kernel<<<2, 256, 0, stream>>>(p0, SA0, SB0, 344);
    pack_bn_kernel<<<2, 256, 0, stream>>>(p1, SA1, SB1, 352);
    pack_bn_kernel<<<3, 256, 0, stream>>>(p2, SA2, SB2, 686);
    pack_bn_kernel<<<3, 256, 0, stream>>>(p3, SA3, SB3, 679);
    pack_bn_kernel<<<5, 256, 0, stream>>>(p4, SA4, SB4, 1246);
    pack_bn_kernel<<<4, 256, 0, stream>>>(p5, SA5, SB5, 973);
    pack_fc_kernel<<<10, 256, 0, stream>>>(fcw, WFp);

    // conv layers: conv_v6f<H,W,TH,TW,NIMG,KWIN,OCG_T,OCW,COUT,POOL>
    conv_v6f<32, 32, 16, 32, 1,  1, 12,  6, 344, false>
        <<<dim3(512, 6), 256, 0, stream>>>(A0, WB0, SA0, SB0, A1);
    conv_v6f<32, 32, 16, 32, 1,  6, 12,  6, 352, true>
        <<<dim3(512, 6), 256, 0, stream>>>(A1, WB1, SA1, SB1, A2);
    conv_v6f<16, 16, 16, 16, 2,  6, 24, 11, 686, false>
        <<<dim3(128, 11), 256, 0, stream>>>(A2, WB2, SA2, SB2, A3);
    conv_v6f<16, 16, 16, 16, 2, 11, 24, 11, 679, true>
        <<<dim3(128, 11), 256, 0, stream>>>(A3, WB3, SA3, SB3, A4);
    conv_m8f<11, 40, 20, 1246, false>
        <<<dim3(64, 20), 256, 0, stream>>>(A4, WB4, SA4, SB4, A5);
    conv_m8f<20, 32, 16, 973, true>
        <<<dim3(64, 16), 256, 0, stream>>>(A5, WB5, SA5, SB5, A6);

    fc_kernel<<<10, 256, 0, stream>>>(A6, WFp, fcb, out);
}

// Round 2
// 1839.644 us; speedup vs baseline: 1.6787x; 1.6787x over previous
//
#include <hip/hip_runtime.h>
#include <stdint.h>

typedef unsigned long long u64;
typedef int v4i  __attribute__((ext_vector_type(4)));
typedef int v8i  __attribute__((ext_vector_type(8)));
typedef float v16f __attribute__((ext_vector_type(16)));

// MX-fp4 MFMA, scales = 1.0 (E8M0 127 in every byte), fmt 4 = FP4 for A and B.
// Data duplicated into both halves of the 8-reg operand to be robust to the
// fp4 register-placement convention ([0:3] vs [4:7]).
static __device__ __forceinline__ v16f mfma_fp4(v4i a, v4i b, v16f c) {
    v8i A, B;
    A[0] = a[0]; A[1] = a[1]; A[2] = a[2]; A[3] = a[3];
    A[4] = a[0]; A[5] = a[1]; A[6] = a[2]; A[7] = a[3];
    B[0] = b[0]; B[1] = b[1]; B[2] = b[2]; B[3] = b[3];
    B[4] = b[0]; B[5] = b[1]; B[6] = b[2]; B[7] = b[3];
    return __builtin_amdgcn_mfma_scale_f32_32x32x64_f8f6f4(
        A, B, c, 4, 4, 0, 0x7F7F7F7F, 0, 0x7F7F7F7F);
}

static __device__ __forceinline__ void gload_lds16(const void* g, void* l) {
    __builtin_amdgcn_global_load_lds(
        (const __attribute__((address_space(1))) unsigned int*)g,
        (__attribute__((address_space(3))) unsigned int*)l, 16, 0, 0);
}

// ---------------------------------------------------------------------------
// Pack input x [256,3,32,32] f32 -> A0 [256][32][32] u64 (bits 0..2 = sign>0)
// (single plane -> plane-major trivially identical)
// ---------------------------------------------------------------------------
__global__ void pack_input_kernel(const float* __restrict__ x, u64* __restrict__ a0)
{
    int idx = blockIdx.x * blockDim.x + threadIdx.x;
    if (idx >= 256 * 1024) return;
    int b = idx >> 10, pix = idx & 1023;
    const float* xp = x + (size_t)b * 3072 + pix;
    u64 wd = 0;
    if (xp[0]    > 0.f) wd |= 1ull;
    if (xp[1024] > 0.f) wd |= 2ull;
    if (xp[2048] > 0.f) wd |= 4ull;
    a0[idx] = wd;
}

// ---------------------------------------------------------------------------
// w [O][C][3][3] f32 -> fp4 B-fragment slab:
//   unit = (t*KWIN + c64)*OCG + og, 1024 B each (64 lanes x 16 B).
//   lane: oc = og*32 + (lane&31), K-half h = lane>>5.
//   dword d, nibble j  <->  channel c = c64*64 + h*32 + d*8 + ((j>>1)+(j&1)*4)
//   nibble: +1 -> 0x2, -1 -> 0xA, invalid channel/oc -> 0x0.
// ---------------------------------------------------------------------------
__global__ void pack_w_fp4(const float* __restrict__ w, unsigned* __restrict__ wb,
                           int O, int C, int KWIN, int OCG)
{
    int idx = blockIdx.x * blockDim.x + threadIdx.x;
    int total = 9 * KWIN * OCG * 64;
    if (idx >= total) return;
    int lane = idx & 63;
    int rest = idx >> 6;
    int og = rest % OCG; rest /= OCG;
    int c64 = rest % KWIN; int t = rest / KWIN;
    int oc = og * 32 + (lane & 31);
    int h = lane >> 5;
    unsigned out[4];
#pragma unroll
    for (int d = 0; d < 4; ++d) {
        unsigned dw = 0;
#pragma unroll
        for (int j = 0; j < 8; ++j) {
            int c = c64 * 64 + h * 32 + d * 8 + ((j >> 1) + (j & 1) * 4);
            unsigned nib = 0;
            if (oc < O && c < C)
                nib = (w[(size_t)(oc * C + c) * 9 + t] > 0.f) ? 0x2u : 0xAu;
            dw |= nib << (4 * j);
        }
        out[d] = dw;
    }
    *(v4i*)(wb + (size_t)idx * 4) = *(v4i*)out;
}

// ---------------------------------------------------------------------------
// BN -> (scale, offset): bn(y) = y*sa + sb
// ---------------------------------------------------------------------------
__global__ void pack_bn_kernel(const float* __restrict__ p, float* __restrict__ sa,
                               float* __restrict__ sb, int C)
{
    int i = blockIdx.x * blockDim.x + threadIdx.x;
    if (i >= C) return;
    float g = p[i], b = p[C + i], m = p[2 * C + i], v = p[3 * C + i];
    float s = g * rsqrtf(v + 1e-5f);
    sa[i] = s;
    sb[i] = fmaf(-m, s, b);
}

// ---------------------------------------------------------------------------
// Pack fc weights [10][15568] f32 -> [10][16 pix][16 words] u64
// ---------------------------------------------------------------------------
__global__ void pack_fc_kernel(const float* __restrict__ fcw, u64* __restrict__ wfc)
{
    int idx = blockIdx.x * blockDim.x + threadIdx.x;
    if (idx >= 10 * 256) return;
    int w = idx & 15;
    int p = (idx >> 4) & 15;
    int k = idx >> 8;
    u64 word = 0;
    for (int c2 = 0; c2 < 64; ++c2) {
        int c = w * 64 + c2;
        if (c < 973) {
            if (fcw[(size_t)k * 15568 + c * 16 + p] > 0.f) word |= (1ull << c2);
        }
    }
    wfc[idx] = word;
}

// ---------------------------------------------------------------------------
// 32 sign bits -> 32 fp4 nibbles (16 B), channel order d*8 + perm(j),
// perm(j) = (j>>1)+(j&1)*4 (matches pack_w_fp4). bit=1 -> 0x2 (+1), else 0xA.
// ---------------------------------------------------------------------------
static __device__ __forceinline__ v4i fp4_unpack32(unsigned wh)
{
    v4i r;
#pragma unroll
    for (int d = 0; d < 4; ++d) {
        unsigned b = (wh >> (8 * d)) & 0xffu;
        unsigned lo = ((b & 0xFu) * 0x00204081u) & 0x01010101u;
        unsigned hi = ((b >> 4)   * 0x00204081u) & 0x01010101u;
        unsigned spread = lo | (hi << 4);
        r[d] = (int)(0xAAAAAAAAu - (spread << 3));
    }
    return r;
}

// ---------------------------------------------------------------------------
// fp4 conv, big layers. Round-0 structure (A plane single-buffered at a FIXED
// LDS address; no staging state held across the MFMA phase) plus:
//   - plane-major act layout [c64][pix] -> coalesced u64 act loads
//   - staging = issue-all-loads then unpack-all (one latency exposure)
//   - hoisted cell address precompute (no per-chunk div/mod)
//   - B slab double-buffered; DMA for chunk c+1 issued before taps(c)
//     (global_load_lds holds no registers; drained by the post-tap barrier
//      after ~5k cycles in flight -> free)
// LDS layout: [B0 18KB][B1 18KB (KWIN>1)][A plane 2*PLANE]
// ---------------------------------------------------------------------------
template <int H, int W, int TH, int TW, int NIMG, int KWIN, int OCG_T, int OCW,
          int COUT, bool POOL>
__global__ __launch_bounds__(256, 2)
void conv_v6f(const u64* __restrict__ act, const char* __restrict__ wb,
              const float* __restrict__ sA, const float* __restrict__ sB,
              u64* __restrict__ outp)
{
    constexpr int CW = TW + 2;
    constexpr int CELLS_I = (TH + 2) * CW;
    constexpr int CELLS = NIMG * CELLS_I;
    constexpr int PLANE = CELLS * 16;
    constexpr int BSZ = 18432;              // 18 units x 1KB
    constexpr int NBB = (KWIN > 1) ? 2 : 1;
    constexpr int AOFS = NBB * BSZ;
    constexpr int NCELL = (CELLS + 255) / 256;
    constexpr size_t NPX  = (size_t)256 * H * W;                       // input plane
    constexpr size_t NPXO = POOL ? ((size_t)256 * (H / 2) * (W / 2))
                                 : ((size_t)256 * H * W);              // output plane
    __shared__ __attribute__((aligned(16))) char smem[AOFS + 2 * PLANE];

    const int tid  = threadIdx.x;
    const int lane = tid & 63;
    const int wm   = tid >> 6;
    const int h    = lane >> 5;
    const int m    = lane & 31;

    int b0i, y0;
    if constexpr (NIMG == 1) {
        b0i = blockIdx.x >> 1;
        y0 = (blockIdx.x & 1) * TH;
    } else {
        b0i = blockIdx.x * NIMG;
        y0 = 0;
    }

    const int ocg0 = blockIdx.y * 2;
    const int gw   = blockIdx.y;

    int aoff[4];
#pragma unroll
    for (int ag = 0; ag < 4; ++ag) {
        int p = wm * 128 + ag * 32 + m;
        int img = p / (TH * TW);
        int pp = p % (TH * TW);
        aoff[ag] = ((img * CELLS_I + (pp / TW) * CW + (pp % TW)) << 4) + h * PLANE;
    }

    // ---- precompute per-thread cell pixel index (-1 = OOB); zero OOB once ----
    int cpx[NCELL];
    int coff[NCELL];
#pragma unroll
    for (int i = 0; i < NCELL; ++i) {
        cpx[i] = -1; coff[i] = 0;
        int cell = tid + i * 256;
        if (cell < CELLS) {
            int img, c2;
            if constexpr (NIMG == 1) { img = 0; c2 = cell; }
            else { img = cell / CELLS_I; c2 = cell % CELLS_I; }
            int cy = c2 / CW, cx = c2 % CW;
            int gy = y0 + cy - 1, gx = cx - 1;
            coff[i] = AOFS + cell * 16;
            if ((unsigned)gy < (unsigned)H && (unsigned)gx < (unsigned)W) {
                cpx[i] = (b0i + img) * (H * W) + gy * W + gx;
            } else {
                v4i z = {0, 0, 0, 0};
                *(v4i*)(smem + coff[i])         = z;
                *(v4i*)(smem + coff[i] + PLANE) = z;
            }
        }
    }

    // ---- staging helpers (no state survives past each call) ----
    auto stageB = [&](int c) {
        char* bb = smem + ((NBB == 2) ? ((c & 1) * BSZ) : 0);
        for (int u = wm; u < 18; u += 4) {
            int og = u & 1, t = u >> 1;
            const char* gp = wb + ((size_t)((t * KWIN + c) * OCG_T + ocg0 + og)) * 1024
                             + lane * 16;
            gload_lds16(gp, bb + u * 1024);
        }
    };
    auto stageA = [&](int c) {
        u64 wd[NCELL];
#pragma unroll
        for (int i = 0; i < NCELL; ++i)
            wd[i] = (cpx[i] >= 0) ? act[(size_t)c * NPX + cpx[i]] : 0;
#pragma unroll
        for (int i = 0; i < NCELL; ++i) if (cpx[i] >= 0) {
            char* dst = smem + coff[i];
            *(v4i*)dst           = fp4_unpack32((unsigned)wd[i]);
            *(v4i*)(dst + PLANE) = fp4_unpack32((unsigned)(wd[i] >> 32));
        }
    };

    // ---- prologue: stage chunk 0 (B-DMA + A) ----
    stageB(0);
    stageA(0);
    __syncthreads();   // drains DMA (vmcnt) + LDS writes

    v16f acc[4][2];
#pragma unroll
    for (int ag = 0; ag < 4; ++ag)
#pragma unroll
        for (int o = 0; o < 2; ++o)
#pragma unroll
            for (int i = 0; i < 16; ++i) acc[ag][o][i] = 0.0f;

#pragma unroll 1
    for (int c64 = 0; c64 < KWIN; ++c64) {
        // issue next chunk's B-DMA before taps (no registers; long flight)
        if (c64 + 1 < KWIN) stageB(c64 + 1);

        const char* sb = smem + ((NBB == 2) ? ((c64 & 1) * BSZ) : 0);

        // ---- K-steps: one tap = one K=64 MFMA per acc tile ----
#pragma unroll
        for (int t = 0; t < 9; ++t) {
            const int aimm = AOFS + (((t / 3) * CW) + (t % 3)) * 16;
            v4i b0 = *(const v4i*)(sb + (t * 2 + 0) * 1024 + lane * 16);
            v4i b1 = *(const v4i*)(sb + (t * 2 + 1) * 1024 + lane * 16);
            v4i a0 = *(const v4i*)(smem + aoff[0] + aimm - AOFS + AOFS);
            v4i a1 = *(const v4i*)(smem + aoff[1] + aimm);
            v4i a2 = *(const v4i*)(smem + aoff[2] + aimm);
            v4i a3 = *(const v4i*)(smem + aoff[3] + aimm);
            a0 = *(const v4i*)(smem + aoff[0] + aimm);
            acc[0][0] = mfma_fp4(a0, b0, acc[0][0]);
            acc[1][0] = mfma_fp4(a1, b0, acc[1][0]);
            acc[2][0] = mfma_fp4(a2, b0, acc[2][0]);
            acc[3][0] = mfma_fp4(a3, b0, acc[3][0]);
            acc[0][1] = mfma_fp4(a0, b1, acc[0][1]);
            acc[1][1] = mfma_fp4(a1, b1, acc[1][1]);
            acc[2][1] = mfma_fp4(a2, b1, acc[2][1]);
            acc[3][1] = mfma_fp4(a3, b1, acc[3][1]);
        }

        if (c64 + 1 < KWIN) {
            __syncthreads();        // all waves done reading A plane; B-DMA drained
            stageA(c64 + 1);        // batched loads -> unpack -> ds_write
            __syncthreads();        // A plane ready
        }
    }

    // ---- epilogue: (pool) + BN-sign -> ballot-packed u64 stores (plane-major) ----
    const int ocA = ocg0 * 32 + m;
    const int ocB = ocA + 32;
    const float fa0 = sA[ocA < COUT ? ocA : 0], fb0 = sB[ocA < COUT ? ocA : 0];
    const float fa1 = sA[ocB < COUT ? ocB : 0], fb1 = sB[ocB < COUT ? ocB : 0];
    u64* outg = outp + (size_t)gw * NPXO;

#pragma unroll
    for (int ag = 0; ag < 4; ++ag) {
        if constexpr (POOL && TW == 32) {
            if (ag & 1) continue;   // vertical pool pairs rows (ag, ag+1)
#pragma unroll
            for (int gi = 0; gi < 8; ++gi) {
                const int g = gi * 2;
                float v0 = fmaxf(fmaxf(acc[ag][0][g], acc[ag][0][g ^ 1]),
                                 fmaxf(acc[ag + 1][0][g], acc[ag + 1][0][g ^ 1]));
                float v1 = fmaxf(fmaxf(acc[ag][1][g], acc[ag][1][g ^ 1]),
                                 fmaxf(acc[ag + 1][1][g], acc[ag + 1][1][g ^ 1]));
                u64 bal0 = __ballot((ocA < COUT) && (fmaf(v0, fa0, fb0) > 0.f));
                u64 bal1 = __ballot((ocB < COUT) && (fmaf(v1, fa1, fb1) > 0.f));
                u64 w_lo = (bal0 & 0xffffffffull) | (bal1 << 32);
                u64 w_hi = (bal0 >> 32) | (bal1 & 0xffffffff00000000ull);
                int pyo  = wm * 2 + (ag >> 1);
                int pxo0 = ((g & 3) >> 1) + 4 * (g >> 2);
                size_t rowb = ((size_t)b0i * (H / 2) + (y0 / 2 + pyo)) * (W / 2);
                if (lane == (ag >> 1) * 16 + gi * 2)
                    outg[rowb + pxo0] = w_lo;
                else if (lane == (ag >> 1) * 16 + gi * 2 + 1)
                    outg[rowb + pxo0 + 2] = w_hi;
            }
        } else if constexpr (POOL) {   // TW == 16, NIMG images
#pragma unroll
            for (int gi = 0; gi < 4; ++gi) {
                const int g = gi * 2;
                float v0 = fmaxf(fmaxf(acc[ag][0][g], acc[ag][0][g ^ 1]),
                                 fmaxf(acc[ag][0][g ^ 8], acc[ag][0][(g ^ 8) | 1]));
                float v1 = fmaxf(fmaxf(acc[ag][1][g], acc[ag][1][g ^ 1]),
                                 fmaxf(acc[ag][1][g ^ 8], acc[ag][1][(g ^ 8) | 1]));
                u64 bal0 = __ballot((ocA < COUT) && (fmaf(v0, fa0, fb0) > 0.f));
                u64 bal1 = __ballot((ocB < COUT) && (fmaf(v1, fa1, fb1) > 0.f));
                u64 w_lo = (bal0 & 0xffffffffull) | (bal1 << 32);
                u64 w_hi = (bal0 >> 32) | (bal1 & 0xffffffff00000000ull);
                int img  = wm >> 1;
                int pyo  = (wm & 1) * 4 + ag;
                int pxo0 = ((g >> 1) & 1) | (((g >> 2) & 1) << 2);
                size_t rowb = ((size_t)(b0i + img) * (TH / 2) + pyo) * (TW / 2);
                if (lane == (ag * 4 + gi) * 2)
                    outg[rowb + pxo0] = w_lo;
                else if (lane == (ag * 4 + gi) * 2 + 1)
                    outg[rowb + pxo0 + 2] = w_hi;
            }
        } else {
#pragma unroll
            for (int reg = 0; reg < 16; ++reg) {
                u64 bal0 = __ballot((ocA < COUT) && (fmaf(acc[ag][0][reg], fa0, fb0) > 0.f));
                u64 bal1 = __ballot((ocB < COUT) && (fmaf(acc[ag][1][reg], fa1, fb1) > 0.f));
                u64 w_lo = (bal0 & 0xffffffffull) | (bal1 << 32);
                u64 w_hi = (bal0 >> 32) | (bal1 & 0xffffffff00000000ull);
                int row  = (reg & 3) + 8 * (reg >> 2);
                int p_lo = wm * 128 + ag * 32 + row;
                int p_hi = p_lo + 4;
                if (lane == reg * 2) {
                    int img, py, px;
                    if constexpr (TW == 32) { img = 0; py = p_lo >> 5; px = p_lo & 31; }
                    else { img = p_lo >> 8; py = (p_lo >> 4) & 15; px = p_lo & 15; }
                    outg[((size_t)(b0i + img) * H + (y0 + py)) * W + px] = w_lo;
                } else if (lane == reg * 2 + 1) {
                    int img, py, px;
                    if constexpr (TW == 32) { img = 0; py = p_hi >> 5; px = p_hi & 31; }
                    else { img = p_hi >> 8; py = (p_hi >> 4) & 15; px = p_hi & 15; }
                    outg[((size_t)(b0i + img) * H + (y0 + py)) * W + px] = w_hi;
                }
            }
        }
    }
}

// ---------------------------------------------------------------------------
// fp4 8x8-layer conv (round-0 structure): block = 4 waves = 4 images x 64 oc;
// wave = own image; B from global with 1-step register prefetch; 9 taps/chunk.
// Act layout plane-major [c64][b*64 + pix] -> coalesced loads.
// ---------------------------------------------------------------------------
template <int KWIN, int OCG, int OCW, int COUT, bool POOL>
__global__ __launch_bounds__(256, 3)
void conv_m8f(const u64* __restrict__ act, const char* __restrict__ wb,
              const float* __restrict__ sA, const float* __restrict__ sB,
              u64* __restrict__ outp)
{
    constexpr int CELLS = 100;
    constexpr int PLANE = CELLS * 16;
    constexpr int IMG = 2 * PLANE;
    constexpr int NPX8 = 16384;              // 256 imgs x 64 px per plane
    constexpr size_t NPXO = POOL ? 4096 : 16384;
    __shared__ __attribute__((aligned(16))) char smem[4 * IMG];

    const int tid  = threadIdx.x;
    const int lane = tid & 63;
    const int wave = tid >> 6;
    const int h    = lane >> 5;
    const int m    = lane & 31;

    const int b = blockIdx.x * 4 + wave;
    const int ocg0 = blockIdx.y * 2;
    const int gw = blockIdx.y;

    int aoff[2];
#pragma unroll
    for (int ph = 0; ph < 2; ++ph) {
        int p = ph * 32 + m;
        aoff[ph] = wave * IMG + ((p >> 3) * 10 + (p & 7)) * 16 + h * PLANE;
    }

    v16f acc[2][2];
#pragma unroll
    for (int a = 0; a < 2; ++a)
#pragma unroll
        for (int o = 0; o < 2; ++o)
#pragma unroll
            for (int i = 0; i < 16; ++i) acc[a][o][i] = 0.0f;

    const u64* actb = act + (size_t)b * 64;

    v4i b0n, b1n;
    {
        const v4i* pn = (const v4i*)(wb + ((size_t)ocg0) * 1024) + lane;
        b0n = pn[0]; b1n = pn[64];
    }

#pragma unroll 1
    for (int c64 = 0; c64 < KWIN; ++c64) {
        for (int cell = lane; cell < CELLS; cell += 64) {
            int cy = cell / 10, cx = cell % 10;
            int gy = cy - 1, gx = cx - 1;
            char* dst = smem + wave * IMG + cell * 16;
            if ((unsigned)gy < 8u && (unsigned)gx < 8u) {
                u64 wd = actb[(size_t)c64 * NPX8 + (gy * 8 + gx)];
                *(v4i*)dst           = fp4_unpack32((unsigned)wd);
                *(v4i*)(dst + PLANE) = fp4_unpack32((unsigned)(wd >> 32));
            } else {
                v4i z = {0, 0, 0, 0};
                *(v4i*)dst           = z;
                *(v4i*)(dst + PLANE) = z;
            }
        }
        __syncthreads();

#pragma unroll
        for (int t = 0; t < 9; ++t) {
            v4i b0 = b0n, b1 = b1n;
            {
                const int tn = (t + 1) % 9;
                const int cn = (t == 8) ? (c64 + 1) : c64;
                const v4i* pn = (const v4i*)(wb + ((size_t)((tn * KWIN + cn) * OCG + ocg0)) * 1024) + lane;
                b0n = pn[0]; b1n = pn[64];
            }
            const int toff = ((t / 3) * 10 + (t % 3)) * 16;
            v4i a0 = *(const v4i*)(smem + aoff[0] + toff);
            v4i a1 = *(const v4i*)(smem + aoff[1] + toff);
            acc[0][0] = mfma_fp4(a0, b0, acc[0][0]);
            acc[1][0] = mfma_fp4(a1, b0, acc[1][0]);
            acc[0][1] = mfma_fp4(a0, b1, acc[0][1]);
            acc[1][1] = mfma_fp4(a1, b1, acc[1][1]);
        }
        __syncthreads();
    }

    const int ocA = ocg0 * 32 + m;
    const int ocB = ocA + 32;
    const float fa0 = sA[ocA < COUT ? ocA : 0], fb0 = sB[ocA < COUT ? ocA : 0];
    const float fa1 = sA[ocB < COUT ? ocB : 0], fb1 = sB[ocB < COUT ? ocB : 0];
    u64* outg = outp + (size_t)gw * NPXO;

#pragma unroll
    for (int ph = 0; ph < 2; ++ph) {
        if constexpr (POOL) {
#pragma unroll
            for (int gi = 0; gi < 4; ++gi) {
                const int g = (gi & 1) * 2 + (gi >> 1) * 8;
                float v0 = fmaxf(fmaxf(acc[ph][0][g], acc[ph][0][g ^ 1]),
                                 fmaxf(acc[ph][0][g ^ 4], acc[ph][0][(g ^ 4) | 1]));
                float v1 = fmaxf(fmaxf(acc[ph][1][g], acc[ph][1][g ^ 1]),
                                 fmaxf(acc[ph][1][g ^ 4], acc[ph][1][(g ^ 4) | 1]));
                u64 bal0 = __ballot((ocA < COUT) && (fmaf(v0, fa0, fb0) > 0.f));
                u64 bal1 = __ballot((ocB < COUT) && (fmaf(v1, fa1, fb1) > 0.f));
                u64 w_lo = (bal0 & 0xffffffffull) | (bal1 << 32);
                u64 w_hi = (bal0 >> 32) | (bal1 & 0xffffffff00000000ull);
                int pyo  = ph * 2 + ((g >> 3) & 1);
                int pxo0 = (g >> 1) & 1;
                int pxo1 = pxo0 | 2;
                size_t rowb = ((size_t)b * 4 + pyo) * 4;
                if (lane == (ph * 4 + gi) * 2)
                    outg[rowb + pxo0] = w_lo;
                else if (lane == (ph * 4 + gi) * 2 + 1)
                    outg[rowb + pxo1] = w_hi;
            }
        } else {
#pragma unroll
            for (int reg = 0; reg < 16; ++reg) {
                u64 bal0 = __ballot((ocA < COUT) && (fmaf(acc[ph][0][reg], fa0, fb0) > 0.f));
                u64 bal1 = __ballot((ocB < COUT) && (fmaf(acc[ph][1][reg], fa1, fb1) > 0.f));
                u64 w_lo = (bal0 & 0xffffffffull) | (bal1 << 32);
                u64 w_hi = (bal0 >> 32) | (bal1 & 0xffffffff00000000ull);
                int row  = (reg & 3) + 8 * (reg >> 2);
                int p_lo = ph * 32 + row;
                int p_hi = p_lo + 4;
                if (lane == reg * 2)
                    outg[((size_t)b * 8 + (p_lo >> 3)) * 8 + (p_lo & 7)] = w_lo;
                else if (lane == reg * 2 + 1)
                    outg[((size_t)b * 8 + (p_hi >> 3)) * 8 + (p_hi & 7)] = w_hi;
            }
        }
    }
}

// ---------------------------------------------------------------------------
// FC: out[b][k] = 15568 - 2*popcount(a6[b] ^ wfc[k]) + fcb[k]   (exact)
// a6 is plane-major: word (b, chan-word w, pixel p) at w*4096 + b*16 + p
// ---------------------------------------------------------------------------
__global__ void fc_kernel(const u64* __restrict__ a6, const u64* __restrict__ wfc,
                          const float* __restrict__ fcb, float* __restrict__ out)
{
    int idx = blockIdx.x * blockDim.x + threadIdx.x;
    if (idx >= 2560) return;
    int k = idx % 10, b = idx / 10;
    const u64* wq = wfc + (size_t)k * 256;
    int pop = 0;
#pragma unroll 8
    for (int q = 0; q < 256; ++q) {
        int w = q & 15, p = q >> 4;
        pop += __popcll(a6[(size_t)w * 4096 + b * 16 + p] ^ wq[q]);
    }
    out[idx] = (float)(15568 - 2 * pop) + fcb[k];
}

// ---------------------------------------------------------------------------
// launch
// ---------------------------------------------------------------------------
extern "C" void kernel_launch(void* const* d_in, const int* in_sizes, int n_in,
                              void* d_out, int out_size, void* d_ws, size_t ws_size,
                              hipStream_t stream)
{
    const float* x   = (const float*)d_in[0];
    const float* w0  = (const float*)d_in[1];
    const float* p0  = (const float*)d_in[2];
    const float* w1  = (const float*)d_in[3];
    const float* p1  = (const float*)d_in[4];
    const float* w2  = (const float*)d_in[5];
    const float* p2  = (const float*)d_in[6];
    const float* w3  = (const float*)d_in[7];
    const float* p3  = (const float*)d_in[8];
    const float* w4  = (const float*)d_in[9];
    const float* p4  = (const float*)d_in[10];
    const float* w5  = (const float*)d_in[11];
    const float* p5  = (const float*)d_in[12];
    const float* fcw = (const float*)d_in[13];
    const float* fcb = (const float*)d_in[14];
    float* out = (float*)d_out;

    u64* WS = (u64*)d_ws;
    u64* A0 = WS;                  // [256*32*32]            = 262144
    u64* A1 = A0 + 262144;         // [6][256*32*32]         = 1572864
    u64* A2 = A1 + 1572864;        // [6][256*16*16]         = 393216
    u64* A3 = A2 + 393216;         // [11][256*16*16]        = 720896
    u64* A4 = A3 + 720896;         // [11][256*8*8]          = 180224
    u64* A5 = A4 + 180224;         // [20][256*8*8]          = 327680
    u64* A6 = A5 + 327680;         // [16][256*4*4]          = 65536
    u64* WFp = A6 + 65536;         // 2560
    // fp4 weight slabs: 9*KWIN*OCG KB each
    char* WB0 = (char*)(WFp + 2560);   //   110,592 (KWIN=1,  OCG=12)
    char* WB1 = WB0 + 110592;          //   663,552 (KWIN=6,  OCG=12)
    char* WB2 = WB1 + 663552;          // 1,327,104 (KWIN=6,  OCG=24)
    char* WB3 = WB2 + 1327104;         // 2,433,024 (KWIN=11, OCG=24)
    char* WB4 = WB3 + 2433024;         // 4,055,040 (KWIN=11, OCG=40)
    char* WB5 = WB4 + 4055040;         // 5,898,240 (KWIN=20, OCG=32)
    float* SA0 = (float*)(WB5 + 5898240);
    float* SB0 = SA0 + 1280;
    float* SA1 = SB0 + 1280;
    float* SB1 = SA1 + 1280;
    float* SA2 = SB1 + 1280;
    float* SB2 = SA2 + 1280;
    float* SA3 = SB2 + 1280;
    float* SB3 = SA3 + 1280;
    float* SA4 = SB3 + 1280;
    float* SB4 = SA4 + 1280;
    float* SA5 = SB4 + 1280;
    float* SB5 = SA5 + 1280;
    // total ws ~= 43 MB

    pack_input_kernel<<<1024, 256, 0, stream>>>(x, A0);
    pack_w_fp4<<<(9 * 1 * 12 * 64 + 255) / 256, 256, 0, stream>>>(w0, (unsigned*)WB0, 344, 3, 1, 12);
    pack_w_fp4<<<(9 * 6 * 12 * 64 + 255) / 256, 256, 0, stream>>>(w1, (unsigned*)WB1, 352, 344, 6, 12);
    pack_w_fp4<<<(9 * 6 * 24 * 64 + 255) / 256, 256, 0, stream>>>(w2, (unsigned*)WB2, 686, 352, 6, 24);
    pack_w_fp4<<<(9 * 11 * 24 * 64 + 255) / 256, 256, 0, stream>>>(w3, (unsigned*)WB3, 679, 686, 11, 24);
    pack_w_fp4<<<(9 * 11 * 40 * 64 + 255) / 256, 256, 0, stream>>>(w4, (unsigned*)WB4, 1246, 679, 11, 40);
    pack_w_fp4<<<(9 * 20 * 32 * 64 + 255) / 256, 256, 0, stream>>>(w5, (unsigned*)WB5, 973, 1246, 20, 32);
    pack_bn_kernel<<<2, 256, 0, stream>>>(p0, SA0, SB0, 344);
    pack_bn_kernel<<<2, 256, 0, stream>>>(p1, SA1, SB1, 352);
    pack_bn_kernel<<<3, 256, 0, stream>>>(p2, SA2, SB2, 686);
    pack_bn_kernel<<<3, 256, 0, stream>>>(p3, SA3, SB3, 679);
    pack_bn_kernel<<<5, 256, 0, stream>>>(p4, SA4, SB4, 1246);
    pack_bn_kernel<<<4, 256, 0, stream>>>(p5, SA5, SB5, 973);
    pack_fc_kernel<<<10, 256, 0, stream>>>(fcw, WFp);

    // conv layers: conv_v6f<H,W,TH,TW,NIMG,KWIN,OCG_T,OCW,COUT,POOL>
    conv_v6f<32, 32, 16, 32, 1,  1, 12,  6, 344, false>
        <<<dim3(512, 6), 256, 0, stream>>>(A0, WB0, SA0, SB0, A1);
    conv_v6f<32, 32, 16, 32, 1,  6, 12,  6, 352, true>
        <<<dim3(512, 6), 256, 0, stream>>>(A1, WB1, SA1, SB1, A2);
    conv_v6f<16, 16, 16, 16, 2,  6, 24, 11, 686, false>
        <<<dim3(128, 11), 256, 0, stream>>>(A2, WB2, SA2, SB2, A3);
    conv_v6f<16, 16, 16, 16, 2, 11, 24, 11, 679, true>
        <<<dim3(128, 11), 256, 0, stream>>>(A3, WB3, SA3, SB3, A4);
    conv_m8f<11, 40, 20, 1246, false>
        <<<dim3(64, 20), 256, 0, stream>>>(A4, WB4, SA4, SB4, A5);
    conv_m8f<20, 32, 16, 973, true>
        <<<dim3(64, 16), 256, 0, stream>>>(A5, WB5, SA5, SB5, A6);

    fc_kernel<<<10, 256, 0, stream>>>(A6, WFp, fcb, out);
}

// Round 3
// 937.974 us; speedup vs baseline: 3.2924x; 1.9613x over previous
//
#include <hip/hip_runtime.h>
#include <stdint.h>

typedef unsigned long long u64;
typedef int v4i  __attribute__((ext_vector_type(4)));
typedef int v8i  __attribute__((ext_vector_type(8)));
typedef float v16f __attribute__((ext_vector_type(16)));

// MX-fp4 MFMA, scales = 1.0 (E8M0 127 in every byte), fmt 4 = FP4 for A and B.
// Data duplicated into both halves of the 8-reg operand to be robust to the
// fp4 register-placement convention ([0:3] vs [4:7]).
static __device__ __forceinline__ v16f mfma_fp4(v4i a, v4i b, v16f c) {
    v8i A, B;
    A[0] = a[0]; A[1] = a[1]; A[2] = a[2]; A[3] = a[3];
    A[4] = a[0]; A[5] = a[1]; A[6] = a[2]; A[7] = a[3];
    B[0] = b[0]; B[1] = b[1]; B[2] = b[2]; B[3] = b[3];
    B[4] = b[0]; B[5] = b[1]; B[6] = b[2]; B[7] = b[3];
    return __builtin_amdgcn_mfma_scale_f32_32x32x64_f8f6f4(
        A, B, c, 4, 4, 0, 0x7F7F7F7F, 0, 0x7F7F7F7F);
}

static __device__ __forceinline__ void gload_lds16(const void* g, void* l) {
    __builtin_amdgcn_global_load_lds(
        (const __attribute__((address_space(1))) unsigned int*)g,
        (__attribute__((address_space(3))) unsigned int*)l, 16, 0, 0);
}

// ---------------------------------------------------------------------------
// Pack input x [256,3,32,32] f32 -> A0 [256*32*32] u64 (bits 0..2 = sign>0)
// ---------------------------------------------------------------------------
__global__ void pack_input_kernel(const float* __restrict__ x, u64* __restrict__ a0)
{
    int idx = blockIdx.x * blockDim.x + threadIdx.x;
    if (idx >= 256 * 1024) return;
    int b = idx >> 10, pix = idx & 1023;
    const float* xp = x + (size_t)b * 3072 + pix;
    u64 wd = 0;
    if (xp[0]    > 0.f) wd |= 1ull;
    if (xp[1024] > 0.f) wd |= 2ull;
    if (xp[2048] > 0.f) wd |= 4ull;
    a0[idx] = wd;
}

// ---------------------------------------------------------------------------
// w [O][C][3][3] f32 -> fp4 B-fragment slab:
//   unit = (t*KWIN + c64)*OCG + og, 1024 B each (64 lanes x 16 B).
//   lane: oc = og*32 + (lane&31), K-half h = lane>>5.
//   dword d, nibble j  <->  channel c = c64*64 + h*32 + d*8 + ((j>>1)+(j&1)*4)
//   nibble: +1 -> 0x2, -1 -> 0xA, invalid channel/oc -> 0x0.
// ---------------------------------------------------------------------------
__global__ void pack_w_fp4(const float* __restrict__ w, unsigned* __restrict__ wb,
                           int O, int C, int KWIN, int OCG)
{
    int idx = blockIdx.x * blockDim.x + threadIdx.x;
    int total = 9 * KWIN * OCG * 64;
    if (idx >= total) return;
    int lane = idx & 63;
    int rest = idx >> 6;
    int og = rest % OCG; rest /= OCG;
    int c64 = rest % KWIN; int t = rest / KWIN;
    int oc = og * 32 + (lane & 31);
    int h = lane >> 5;
    unsigned out[4];
#pragma unroll
    for (int d = 0; d < 4; ++d) {
        unsigned dw = 0;
#pragma unroll
        for (int j = 0; j < 8; ++j) {
            int c = c64 * 64 + h * 32 + d * 8 + ((j >> 1) + (j & 1) * 4);
            unsigned nib = 0;
            if (oc < O && c < C)
                nib = (w[(size_t)(oc * C + c) * 9 + t] > 0.f) ? 0x2u : 0xAu;
            dw |= nib << (4 * j);
        }
        out[d] = dw;
    }
    *(v4i*)(wb + (size_t)idx * 4) = *(v4i*)out;
}

// ---------------------------------------------------------------------------
// BN -> (scale, offset): bn(y) = y*sa + sb
// ---------------------------------------------------------------------------
__global__ void pack_bn_kernel(const float* __restrict__ p, float* __restrict__ sa,
                               float* __restrict__ sb, int C)
{
    int i = blockIdx.x * blockDim.x + threadIdx.x;
    if (i >= C) return;
    float g = p[i], b = p[C + i], m = p[2 * C + i], v = p[3 * C + i];
    float s = g * rsqrtf(v + 1e-5f);
    sa[i] = s;
    sb[i] = fmaf(-m, s, b);
}

// ---------------------------------------------------------------------------
// Pack fc weights [10][15568] f32 -> [10][16 pix][16 words] u64
// ---------------------------------------------------------------------------
__global__ void pack_fc_kernel(const float* __restrict__ fcw, u64* __restrict__ wfc)
{
    int idx = blockIdx.x * blockDim.x + threadIdx.x;
    if (idx >= 10 * 256) return;
    int w = idx & 15;
    int p = (idx >> 4) & 15;
    int k = idx >> 8;
    u64 word = 0;
    for (int c2 = 0; c2 < 64; ++c2) {
        int c = w * 64 + c2;
        if (c < 973) {
            if (fcw[(size_t)k * 15568 + c * 16 + p] > 0.f) word |= (1ull << c2);
        }
    }
    wfc[idx] = word;
}

// ---------------------------------------------------------------------------
// 32 sign bits -> 32 fp4 nibbles (16 B), channel order d*8 + perm(j),
// perm(j) = (j>>1)+(j&1)*4 (matches pack_w_fp4). bit=1 -> 0x2 (+1), else 0xA.
// ---------------------------------------------------------------------------
static __device__ __forceinline__ v4i fp4_unpack32(unsigned wh)
{
    v4i r;
#pragma unroll
    for (int d = 0; d < 4; ++d) {
        unsigned b = (wh >> (8 * d)) & 0xffu;
        unsigned lo = ((b & 0xFu) * 0x00204081u) & 0x01010101u;
        unsigned hi = ((b >> 4)   * 0x00204081u) & 0x01010101u;
        unsigned spread = lo | (hi << 4);
        r[d] = (int)(0xAAAAAAAAu - (spread << 3));
    }
    return r;
}

// ---------------------------------------------------------------------------
// fp4 conv, big layers. ROUND-0 STRUCTURE (known-good allocator outcome:
// VGPR~100, acc in AGPRs, zero spill). Only change vs round 0: activation
// layout is plane-major [c64][pix] -> staging loads are lane-consecutive
// (coalesced), and output stores use the matching plane-major base.
// Block = 4 waves = 512 px x 64 oc. Per 64-ch chunk: B staged by async DMA
// (18 KB), A unpacked bits->fp4 planes; K-loop = 9 taps x 8 MFMA K=64.
// ---------------------------------------------------------------------------
template <int H, int W, int TH, int TW, int NIMG, int KWIN, int OCG_T, int OCW,
          int COUT, bool POOL>
__global__ __launch_bounds__(256, 2)
void conv_v6f(const u64* __restrict__ act, const char* __restrict__ wb,
              const float* __restrict__ sA, const float* __restrict__ sB,
              u64* __restrict__ outp)
{
    constexpr int CW = TW + 2;
    constexpr int CELLS_I = (TH + 2) * CW;
    constexpr int CELLS = NIMG * CELLS_I;
    constexpr int PLANE = CELLS * 16;
    constexpr int BSZ = 18432;              // 18 units x 1KB
    constexpr size_t NPX  = (size_t)256 * H * W;                       // input plane
    constexpr size_t NPXO = POOL ? ((size_t)256 * (H / 2) * (W / 2))
                                 : ((size_t)256 * H * W);              // output plane
    __shared__ __attribute__((aligned(16))) char smem[BSZ + 2 * PLANE];

    const int tid  = threadIdx.x;
    const int lane = tid & 63;
    const int wm   = tid >> 6;
    const int h    = lane >> 5;
    const int m    = lane & 31;

    int b0i, y0;
    if constexpr (NIMG == 1) {
        b0i = blockIdx.x >> 1;
        y0 = (blockIdx.x & 1) * TH;
    } else {
        b0i = blockIdx.x * NIMG;
        y0 = 0;
    }

    const int ocg0 = blockIdx.y * 2;
    const int gw   = blockIdx.y;

    int aoff[4];
#pragma unroll
    for (int ag = 0; ag < 4; ++ag) {
        int p = wm * 128 + ag * 32 + m;
        int img = p / (TH * TW);
        int pp = p % (TH * TW);
        aoff[ag] = ((img * CELLS_I + (pp / TW) * CW + (pp % TW)) << 4) + h * PLANE;
    }

    v16f acc[4][2];
#pragma unroll
    for (int ag = 0; ag < 4; ++ag)
#pragma unroll
        for (int o = 0; o < 2; ++o)
#pragma unroll
            for (int i = 0; i < 16; ++i) acc[ag][o][i] = 0.0f;

#pragma unroll 1
    for (int c64 = 0; c64 < KWIN; ++c64) {
        // ---- B stage: 18 x 1KB units via async global->LDS DMA ----
        for (int u = wm; u < 18; u += 4) {
            int og = u & 1, t = u >> 1;
            const char* gp = wb + ((size_t)((t * KWIN + c64) * OCG_T + ocg0 + og)) * 1024
                             + lane * 16;
            gload_lds16(gp, smem + u * 1024);
        }
        // ---- A stage: unpack bit-words into 2 fp4 planes (coalesced loads) ----
        for (int cell = tid; cell < CELLS; cell += 256) {
            int img, c2;
            if constexpr (NIMG == 1) { img = 0; c2 = cell; }
            else { img = cell / CELLS_I; c2 = cell % CELLS_I; }
            int cy = c2 / CW, cx = c2 % CW;
            int gy = y0 + cy - 1, gx = cx - 1;
            char* dst = smem + BSZ + cell * 16;
            if ((unsigned)gy < (unsigned)H && (unsigned)gx < (unsigned)W) {
                u64 wd = act[(size_t)c64 * NPX
                             + (size_t)(b0i + img) * (H * W) + gy * W + gx];
                *(v4i*)dst           = fp4_unpack32((unsigned)wd);
                *(v4i*)(dst + PLANE) = fp4_unpack32((unsigned)(wd >> 32));
            } else {
                v4i z = {0, 0, 0, 0};
                *(v4i*)dst           = z;
                *(v4i*)(dst + PLANE) = z;
            }
        }
        __syncthreads();   // drains DMA (vmcnt) + LDS writes

        // ---- K-steps: one tap = one K=64 MFMA per acc tile ----
#pragma unroll
        for (int t = 0; t < 9; ++t) {
            const int aimm = BSZ + (((t / 3) * CW) + (t % 3)) * 16;
            v4i b0 = *(const v4i*)(smem + (t * 2 + 0) * 1024 + lane * 16);
            v4i b1 = *(const v4i*)(smem + (t * 2 + 1) * 1024 + lane * 16);
            v4i a0 = *(const v4i*)(smem + aoff[0] + aimm);
            v4i a1 = *(const v4i*)(smem + aoff[1] + aimm);
            v4i a2 = *(const v4i*)(smem + aoff[2] + aimm);
            v4i a3 = *(const v4i*)(smem + aoff[3] + aimm);
            acc[0][0] = mfma_fp4(a0, b0, acc[0][0]);
            acc[1][0] = mfma_fp4(a1, b0, acc[1][0]);
            acc[2][0] = mfma_fp4(a2, b0, acc[2][0]);
            acc[3][0] = mfma_fp4(a3, b0, acc[3][0]);
            acc[0][1] = mfma_fp4(a0, b1, acc[0][1]);
            acc[1][1] = mfma_fp4(a1, b1, acc[1][1]);
            acc[2][1] = mfma_fp4(a2, b1, acc[2][1]);
            acc[3][1] = mfma_fp4(a3, b1, acc[3][1]);
        }
        __syncthreads();
    }

    // ---- epilogue: (pool) + BN-sign -> ballot-packed u64 stores (plane-major) ----
    const int ocA = ocg0 * 32 + m;
    const int ocB = ocA + 32;
    const float fa0 = sA[ocA < COUT ? ocA : 0], fb0 = sB[ocA < COUT ? ocA : 0];
    const float fa1 = sA[ocB < COUT ? ocB : 0], fb1 = sB[ocB < COUT ? ocB : 0];
    u64* outg = outp + (size_t)gw * NPXO;

#pragma unroll
    for (int ag = 0; ag < 4; ++ag) {
        if constexpr (POOL && TW == 32) {
            if (ag & 1) continue;   // vertical pool pairs rows (ag, ag+1)
#pragma unroll
            for (int gi = 0; gi < 8; ++gi) {
                const int g = gi * 2;
                float v0 = fmaxf(fmaxf(acc[ag][0][g], acc[ag][0][g ^ 1]),
                                 fmaxf(acc[ag + 1][0][g], acc[ag + 1][0][g ^ 1]));
                float v1 = fmaxf(fmaxf(acc[ag][1][g], acc[ag][1][g ^ 1]),
                                 fmaxf(acc[ag + 1][1][g], acc[ag + 1][1][g ^ 1]));
                u64 bal0 = __ballot((ocA < COUT) && (fmaf(v0, fa0, fb0) > 0.f));
                u64 bal1 = __ballot((ocB < COUT) && (fmaf(v1, fa1, fb1) > 0.f));
                u64 w_lo = (bal0 & 0xffffffffull) | (bal1 << 32);
                u64 w_hi = (bal0 >> 32) | (bal1 & 0xffffffff00000000ull);
                int pyo  = wm * 2 + (ag >> 1);
                int pxo0 = ((g & 3) >> 1) + 4 * (g >> 2);
                size_t rowb = ((size_t)b0i * (H / 2) + (y0 / 2 + pyo)) * (W / 2);
                if (lane == (ag >> 1) * 16 + gi * 2)
                    outg[rowb + pxo0] = w_lo;
                else if (lane == (ag >> 1) * 16 + gi * 2 + 1)
                    outg[rowb + pxo0 + 2] = w_hi;
            }
        } else if constexpr (POOL) {   // TW == 16, NIMG images
#pragma unroll
            for (int gi = 0; gi < 4; ++gi) {
                const int g = gi * 2;
                float v0 = fmaxf(fmaxf(acc[ag][0][g], acc[ag][0][g ^ 1]),
                                 fmaxf(acc[ag][0][g ^ 8], acc[ag][0][(g ^ 8) | 1]));
                float v1 = fmaxf(fmaxf(acc[ag][1][g], acc[ag][1][g ^ 1]),
                                 fmaxf(acc[ag][1][g ^ 8], acc[ag][1][(g ^ 8) | 1]));
                u64 bal0 = __ballot((ocA < COUT) && (fmaf(v0, fa0, fb0) > 0.f));
                u64 bal1 = __ballot((ocB < COUT) && (fmaf(v1, fa1, fb1) > 0.f));
                u64 w_lo = (bal0 & 0xffffffffull) | (bal1 << 32);
                u64 w_hi = (bal0 >> 32) | (bal1 & 0xffffffff00000000ull);
                int img  = wm >> 1;
                int pyo  = (wm & 1) * 4 + ag;
                int pxo0 = ((g >> 1) & 1) | (((g >> 2) & 1) << 2);
                size_t rowb = ((size_t)(b0i + img) * (TH / 2) + pyo) * (TW / 2);
                if (lane == (ag * 4 + gi) * 2)
                    outg[rowb + pxo0] = w_lo;
                else if (lane == (ag * 4 + gi) * 2 + 1)
                    outg[rowb + pxo0 + 2] = w_hi;
            }
        } else {
#pragma unroll
            for (int reg = 0; reg < 16; ++reg) {
                u64 bal0 = __ballot((ocA < COUT) && (fmaf(acc[ag][0][reg], fa0, fb0) > 0.f));
                u64 bal1 = __ballot((ocB < COUT) && (fmaf(acc[ag][1][reg], fa1, fb1) > 0.f));
                u64 w_lo = (bal0 & 0xffffffffull) | (bal1 << 32);
                u64 w_hi = (bal0 >> 32) | (bal1 & 0xffffffff00000000ull);
                int row  = (reg & 3) + 8 * (reg >> 2);
                int p_lo = wm * 128 + ag * 32 + row;
                int p_hi = p_lo + 4;
                if (lane == reg * 2) {
                    int img, py, px;
                    if constexpr (TW == 32) { img = 0; py = p_lo >> 5; px = p_lo & 31; }
                    else { img = p_lo >> 8; py = (p_lo >> 4) & 15; px = p_lo & 15; }
                    outg[((size_t)(b0i + img) * H + (y0 + py)) * W + px] = w_lo;
                } else if (lane == reg * 2 + 1) {
                    int img, py, px;
                    if constexpr (TW == 32) { img = 0; py = p_hi >> 5; px = p_hi & 31; }
                    else { img = p_hi >> 8; py = (p_hi >> 4) & 15; px = p_hi & 15; }
                    outg[((size_t)(b0i + img) * H + (y0 + py)) * W + px] = w_hi;
                }
            }
        }
    }
}

// ---------------------------------------------------------------------------
// fp4 8x8-layer conv (round-0 structure): block = 4 waves = 4 images x 64 oc;
// wave = own image; B from global with 1-step register prefetch; 9 taps/chunk.
// Act layout plane-major [c64][b*64 + pix] -> coalesced loads.
// ---------------------------------------------------------------------------
template <int KWIN, int OCG, int OCW, int COUT, bool POOL>
__global__ __launch_bounds__(256, 3)
void conv_m8f(const u64* __restrict__ act, const char* __restrict__ wb,
              const float* __restrict__ sA, const float* __restrict__ sB,
              u64* __restrict__ outp)
{
    constexpr int CELLS = 100;
    constexpr int PLANE = CELLS * 16;
    constexpr int IMG = 2 * PLANE;
    constexpr int NPX8 = 16384;              // 256 imgs x 64 px per plane
    constexpr size_t NPXO = POOL ? 4096 : 16384;
    __shared__ __attribute__((aligned(16))) char smem[4 * IMG];

    const int tid  = threadIdx.x;
    const int lane = tid & 63;
    const int wave = tid >> 6;
    const int h    = lane >> 5;
    const int m    = lane & 31;

    const int b = blockIdx.x * 4 + wave;
    const int ocg0 = blockIdx.y * 2;
    const int gw = blockIdx.y;

    int aoff[2];
#pragma unroll
    for (int ph = 0; ph < 2; ++ph) {
        int p = ph * 32 + m;
        aoff[ph] = wave * IMG + ((p >> 3) * 10 + (p & 7)) * 16 + h * PLANE;
    }

    v16f acc[2][2];
#pragma unroll
    for (int a = 0; a < 2; ++a)
#pragma unroll
        for (int o = 0; o < 2; ++o)
#pragma unroll
            for (int i = 0; i < 16; ++i) acc[a][o][i] = 0.0f;

    const u64* actb = act + (size_t)b * 64;

    v4i b0n, b1n;
    {
        const v4i* pn = (const v4i*)(wb + ((size_t)ocg0) * 1024) + lane;
        b0n = pn[0]; b1n = pn[64];
    }

#pragma unroll 1
    for (int c64 = 0; c64 < KWIN; ++c64) {
        for (int cell = lane; cell < CELLS; cell += 64) {
            int cy = cell / 10, cx = cell % 10;
            int gy = cy - 1, gx = cx - 1;
            char* dst = smem + wave * IMG + cell * 16;
            if ((unsigned)gy < 8u && (unsigned)gx < 8u) {
                u64 wd = actb[(size_t)c64 * NPX8 + (gy * 8 + gx)];
                *(v4i*)dst           = fp4_unpack32((unsigned)wd);
                *(v4i*)(dst + PLANE) = fp4_unpack32((unsigned)(wd >> 32));
            } else {
                v4i z = {0, 0, 0, 0};
                *(v4i*)dst           = z;
                *(v4i*)(dst + PLANE) = z;
            }
        }
        __syncthreads();

#pragma unroll
        for (int t = 0; t < 9; ++t) {
            v4i b0 = b0n, b1 = b1n;
            {
                const int tn = (t + 1) % 9;
                const int cn = (t == 8) ? (c64 + 1) : c64;
                const v4i* pn = (const v4i*)(wb + ((size_t)((tn * KWIN + cn) * OCG + ocg0)) * 1024) + lane;
                b0n = pn[0]; b1n = pn[64];
            }
            const int toff = ((t / 3) * 10 + (t % 3)) * 16;
            v4i a0 = *(const v4i*)(smem + aoff[0] + toff);
            v4i a1 = *(const v4i*)(smem + aoff[1] + toff);
            acc[0][0] = mfma_fp4(a0, b0, acc[0][0]);
            acc[1][0] = mfma_fp4(a1, b0, acc[1][0]);
            acc[0][1] = mfma_fp4(a0, b1, acc[0][1]);
            acc[1][1] = mfma_fp4(a1, b1, acc[1][1]);
        }
        __syncthreads();
    }

    const int ocA = ocg0 * 32 + m;
    const int ocB = ocA + 32;
    const float fa0 = sA[ocA < COUT ? ocA : 0], fb0 = sB[ocA < COUT ? ocA : 0];
    const float fa1 = sA[ocB < COUT ? ocB : 0], fb1 = sB[ocB < COUT ? ocB : 0];
    u64* outg = outp + (size_t)gw * NPXO;

#pragma unroll
    for (int ph = 0; ph < 2; ++ph) {
        if constexpr (POOL) {
#pragma unroll
            for (int gi = 0; gi < 4; ++gi) {
                const int g = (gi & 1) * 2 + (gi >> 1) * 8;
                float v0 = fmaxf(fmaxf(acc[ph][0][g], acc[ph][0][g ^ 1]),
                                 fmaxf(acc[ph][0][g ^ 4], acc[ph][0][(g ^ 4) | 1]));
                float v1 = fmaxf(fmaxf(acc[ph][1][g], acc[ph][1][g ^ 1]),
                                 fmaxf(acc[ph][1][g ^ 4], acc[ph][1][(g ^ 4) | 1]));
                u64 bal0 = __ballot((ocA < COUT) && (fmaf(v0, fa0, fb0) > 0.f));
                u64 bal1 = __ballot((ocB < COUT) && (fmaf(v1, fa1, fb1) > 0.f));
                u64 w_lo = (bal0 & 0xffffffffull) | (bal1 << 32);
                u64 w_hi = (bal0 >> 32) | (bal1 & 0xffffffff00000000ull);
                int pyo  = ph * 2 + ((g >> 3) & 1);
                int pxo0 = (g >> 1) & 1;
                int pxo1 = pxo0 | 2;
                size_t rowb = ((size_t)b * 4 + pyo) * 4;
                if (lane == (ph * 4 + gi) * 2)
                    outg[rowb + pxo0] = w_lo;
                else if (lane == (ph * 4 + gi) * 2 + 1)
                    outg[rowb + pxo1] = w_hi;
            }
        } else {
#pragma unroll
            for (int reg = 0; reg < 16; ++reg) {
                u64 bal0 = __ballot((ocA < COUT) && (fmaf(acc[ph][0][reg], fa0, fb0) > 0.f));
                u64 bal1 = __ballot((ocB < COUT) && (fmaf(acc[ph][1][reg], fa1, fb1) > 0.f));
                u64 w_lo = (bal0 & 0xffffffffull) | (bal1 << 32);
                u64 w_hi = (bal0 >> 32) | (bal1 & 0xffffffff00000000ull);
                int row  = (reg & 3) + 8 * (reg >> 2);
                int p_lo = ph * 32 + row;
                int p_hi = p_lo + 4;
                if (lane == reg * 2)
                    outg[((size_t)b * 8 + (p_lo >> 3)) * 8 + (p_lo & 7)] = w_lo;
                else if (lane == reg * 2 + 1)
                    outg[((size_t)b * 8 + (p_hi >> 3)) * 8 + (p_hi & 7)] = w_hi;
            }
        }
    }
}

// ---------------------------------------------------------------------------
// FC: out[b][k] = 15568 - 2*popcount(a6[b] ^ wfc[k]) + fcb[k]   (exact)
// a6 is plane-major: word (b, chan-word w, pixel p) at w*4096 + b*16 + p
// ---------------------------------------------------------------------------
__global__ void fc_kernel(const u64* __restrict__ a6, const u64* __restrict__ wfc,
                          const float* __restrict__ fcb, float* __restrict__ out)
{
    int idx = blockIdx.x * blockDim.x + threadIdx.x;
    if (idx >= 2560) return;
    int k = idx % 10, b = idx / 10;
    const u64* wq = wfc + (size_t)k * 256;
    int pop = 0;
#pragma unroll 8
    for (int q = 0; q < 256; ++q) {
        int w = q & 15, p = q >> 4;
        pop += __popcll(a6[(size_t)w * 4096 + b * 16 + p] ^ wq[q]);
    }
    out[idx] = (float)(15568 - 2 * pop) + fcb[k];
}

// ---------------------------------------------------------------------------
// launch
// ---------------------------------------------------------------------------
extern "C" void kernel_launch(void* const* d_in, const int* in_sizes, int n_in,
                              void* d_out, int out_size, void* d_ws, size_t ws_size,
                              hipStream_t stream)
{
    const float* x   = (const float*)d_in[0];
    const float* w0  = (const float*)d_in[1];
    const float* p0  = (const float*)d_in[2];
    const float* w1  = (const float*)d_in[3];
    const float* p1  = (const float*)d_in[4];
    const float* w2  = (const float*)d_in[5];
    const float* p2  = (const float*)d_in[6];
    const float* w3  = (const float*)d_in[7];
    const float* p3  = (const float*)d_in[8];
    const float* w4  = (const float*)d_in[9];
    const float* p4  = (const float*)d_in[10];
    const float* w5  = (const float*)d_in[11];
    const float* p5  = (const float*)d_in[12];
    const float* fcw = (const float*)d_in[13];
    const float* fcb = (const float*)d_in[14];
    float* out = (float*)d_out;

    u64* WS = (u64*)d_ws;
    u64* A0 = WS;                  // [256*32*32]            = 262144
    u64* A1 = A0 + 262144;         // [6][256*32*32]         = 1572864
    u64* A2 = A1 + 1572864;        // [6][256*16*16]         = 393216
    u64* A3 = A2 + 393216;         // [11][256*16*16]        = 720896
    u64* A4 = A3 + 720896;         // [11][256*8*8]          = 180224
    u64* A5 = A4 + 180224;         // [20][256*8*8]          = 327680
    u64* A6 = A5 + 327680;         // [16][256*4*4]          = 65536
    u64* WFp = A6 + 65536;         // 2560
    // fp4 weight slabs: 9*KWIN*OCG KB each
    char* WB0 = (char*)(WFp + 2560);   //   110,592 (KWIN=1,  OCG=12)
    char* WB1 = WB0 + 110592;          //   663,552 (KWIN=6,  OCG=12)
    char* WB2 = WB1 + 663552;          // 1,327,104 (KWIN=6,  OCG=24)
    char* WB3 = WB2 + 1327104;         // 2,433,024 (KWIN=11, OCG=24)
    char* WB4 = WB3 + 2433024;         // 4,055,040 (KWIN=11, OCG=40)
    char* WB5 = WB4 + 4055040;         // 5,898,240 (KWIN=20, OCG=32)
    float* SA0 = (float*)(WB5 + 5898240);
    float* SB0 = SA0 + 1280;
    float* SA1 = SB0 + 1280;
    float* SB1 = SA1 + 1280;
    float* SA2 = SB1 + 1280;
    float* SB2 = SA2 + 1280;
    float* SA3 = SB2 + 1280;
    float* SB3 = SA3 + 1280;
    float* SA4 = SB3 + 1280;
    float* SB4 = SA4 + 1280;
    float* SA5 = SB4 + 1280;
    float* SB5 = SA5 + 1280;
    // total ws ~= 43 MB

    pack_input_kernel<<<1024, 256, 0, stream>>>(x, A0);
    pack_w_fp4<<<(9 * 1 * 12 * 64 + 255) / 256, 256, 0, stream>>>(w0, (unsigned*)WB0, 344, 3, 1, 12);
    pack_w_fp4<<<(9 * 6 * 12 * 64 + 255) / 256, 256, 0, stream>>>(w1, (unsigned*)WB1, 352, 344, 6, 12);
    pack_w_fp4<<<(9 * 6 * 24 * 64 + 255) / 256, 256, 0, stream>>>(w2, (unsigned*)WB2, 686, 352, 6, 24);
    pack_w_fp4<<<(9 * 11 * 24 * 64 + 255) / 256, 256, 0, stream>>>(w3, (unsigned*)WB3, 679, 686, 11, 24);
    pack_w_fp4<<<(9 * 11 * 40 * 64 + 255) / 256, 256, 0, stream>>>(w4, (unsigned*)WB4, 1246, 679, 11, 40);
    pack_w_fp4<<<(9 * 20 * 32 * 64 + 255) / 256, 256, 0, stream>>>(w5, (unsigned*)WB5, 973, 1246, 20, 32);
    pack_bn_kernel<<<2, 256, 0, stream>>>(p0, SA0, SB0, 344);
    pack_bn_kernel<<<2, 256, 0, stream>>>(p1, SA1, SB1, 352);
    pack_bn_kernel<<<3, 256, 0, stream>>>(p2, SA2, SB2, 686);
    pack_bn_kernel<<<3, 256, 0, stream>>>(p3, SA3, SB3, 679);
    pack_bn_kernel<<<5, 256, 0, stream>>>(p4, SA4, SB4, 1246);
    pack_bn_kernel<<<4, 256, 0, stream>>>(p5, SA5, SB5, 973);
    pack_fc_kernel<<<10, 256, 0, stream>>>(fcw, WFp);

    // conv layers: conv_v6f<H,W,TH,TW,NIMG,KWIN,OCG_T,OCW,COUT,POOL>
    conv_v6f<32, 32, 16, 32, 1,  1, 12,  6, 344, false>
        <<<dim3(512, 6), 256, 0, stream>>>(A0, WB0, SA0, SB0, A1);
    conv_v6f<32, 32, 16, 32, 1,  6, 12,  6, 352, true>
        <<<dim3(512, 6), 256, 0, stream>>>(A1, WB1, SA1, SB1, A2);
    conv_v6f<16, 16, 16, 16, 2,  6, 24, 11, 686, false>
        <<<dim3(128, 11), 256, 0, stream>>>(A2, WB2, SA2, SB2, A3);
    conv_v6f<16, 16, 16, 16, 2, 11, 24, 11, 679, true>
        <<<dim3(128, 11), 256, 0, stream>>>(A3, WB3, SA3, SB3, A4);
    conv_m8f<11, 40, 20, 1246, false>
        <<<dim3(64, 20), 256, 0, stream>>>(A4, WB4, SA4, SB4, A5);
    conv_m8f<20, 32, 16, 973, true>
        <<<dim3(64, 16), 256, 0, stream>>>(A5, WB5, SA5, SB5, A6);

    fc_kernel<<<10, 256, 0, stream>>>(A6, WFp, fcb, out);
}